// Round 1
// baseline (123.245 us; speedup 1.0000x reference)
//
#include <hip/hip_runtime.h>

// Problem constants (fixed by setup_inputs): x,y [N,C,H,W] fp32, maxdisp=48.
#define N_ 4
#define C_ 64
#define H_ 128
#define W_ 256
#define D_ 48
#define ROWS (W_ + D_)   // 304 floats per c-slice in LDS (D_ leading zeros)

// One block per (n,h) row. 256 threads = 4 waves; thread t owns w = t.
// LDS: 64 * 304 * 4 B = 77824 B -> 2 blocks/CU. Grid = N*H = 512 = 2/CU exactly.
__global__ __launch_bounds__(256, 2)
void corr1d_kernel(const float* __restrict__ x,
                   const float* __restrict__ y,
                   float* __restrict__ out) {
    __shared__ float ysh[C_][ROWS];

    const int t  = threadIdx.x;
    const int nh = blockIdx.x;
    const int n  = nh / H_;
    const int h  = nh % H_;

    // element offset of [n, c=0, h, w=0]; c-stride is H_*W_
    const size_t in_base = ((size_t)n * C_ * H_ + h) * W_;

    // ---- zero the left pad: C_*D_ = 3072 floats, 12 iterations of 256 ----
    #pragma unroll
    for (int k = 0; k < (C_ * D_) / 256; ++k) {
        int idx = k * 256 + t;
        int c = idx / D_;
        int j = idx % D_;
        ysh[c][j] = 0.0f;
    }

    // ---- stage y row: C_*W_/4 = 4096 float4 chunks, 16 iterations of 256 ----
    // wave-contiguous: each 64-lane wave reads 1 KiB contiguous, 16B/lane.
    #pragma unroll
    for (int k = 0; k < (C_ * W_ / 4) / 256; ++k) {
        int idx = k * 256 + t;          // float4 index
        int c = idx / (W_ / 4);
        int q = idx % (W_ / 4);
        const float4 v = *reinterpret_cast<const float4*>(
            &y[in_base + (size_t)c * (H_ * W_) + q * 4]);
        *reinterpret_cast<float4*>(&ysh[c][D_ + q * 4]) = v;  // 16B-aligned (D_%4==0)
    }

    __syncthreads();

    float acc[D_];
    #pragma unroll
    for (int i = 0; i < D_; ++i) acc[i] = 0.0f;

    const int w = t;

    for (int c = 0; c < C_; ++c) {
        // coalesced: lane w reads consecutive addresses
        const float xv = x[in_base + (size_t)c * (H_ * W_) + w];
        // base &ysh[c][w]; offsets (D_-i)*4 bytes are positive compile-time
        // immediates -> foldable into ds_read2_b32 offset0/offset1.
        const float* yrow = &ysh[c][w];
        #pragma unroll
        for (int i = 0; i < D_; ++i) {
            // corr[i,w] += x[c,w] * y_pad[c][D_ + w - i]
            acc[i] += xv * yrow[D_ - i];
        }
    }

    // ---- write out[n, i, h, w]: coalesced per i ----
    const size_t out_base = ((size_t)n * D_ * H_ + h) * W_ + w;
    #pragma unroll
    for (int i = 0; i < D_; ++i) {
        out[out_base + (size_t)i * (H_ * W_)] = acc[i];
    }
}

extern "C" void kernel_launch(void* const* d_in, const int* in_sizes, int n_in,
                              void* d_out, int out_size, void* d_ws, size_t ws_size,
                              hipStream_t stream) {
    (void)in_sizes; (void)n_in; (void)out_size; (void)d_ws; (void)ws_size;
    const float* x = (const float*)d_in[0];
    const float* y = (const float*)d_in[1];
    // d_in[2] is maxdisp (=48), fixed by the reference setup; hardcoded as D_.
    float* out = (float*)d_out;

    dim3 grid(N_ * H_);   // 512 blocks
    dim3 block(256);
    corr1d_kernel<<<grid, block, 0, stream>>>(x, y, out);
}

// Round 3
// 117.726 us; speedup vs baseline: 1.0469x; 1.0469x over previous
//
#include <hip/hip_runtime.h>

// x,y [N=4, C=64, H=128, W=256] fp32, maxdisp=48 (fixed by setup_inputs).
// out[n,i,h,w] = sum_c x[n,c,h,w] * y[n,c,h,w-i], zero where w-i<0.
#define N_ 4
#define C_ 64
#define H_ 128
#define W_ 256
#define D_ 48
#define HW_ (H_ * W_)

#define WTILE 128               // w-columns per block
#define HALO  D_                // 48 left halo (incl. zero pad at w<0)
#define YCOLS (WTILE + HALO)    // 176 floats per staged y row
#define CCHUNK 16               // channels resident in LDS at once
#define NCHUNK (C_ / CCHUNK)    // 4
#define VT 4                    // w-columns per thread
#define DT 12                   // disparities per thread
#define NIG (D_ / DT)           // 4 disparity groups
#define NTW (WTILE / VT)        // 32 w-threads
#define NTHREADS (NTW * NIG)    // 128 threads = 2 waves

// LDS: y 16*176*4 = 11264 B + x 16*128*4 = 8192 B = 19456 B -> 4+ blocks/CU.
// Grid 1024 blocks = 4/CU exact; 8 waves/CU.
__global__ __launch_bounds__(NTHREADS, 2)
void corr1d_v2(const float* __restrict__ x,
               const float* __restrict__ y,
               float* __restrict__ out) {
    __shared__ __align__(16) float ysh[CCHUNK][YCOLS];
    __shared__ __align__(16) float xsh[CCHUNK][WTILE];

    const int t  = threadIdx.x;
    const int tw = t & (NTW - 1);     // 0..31
    const int ig = t >> 5;            // 0..3 disparity group
    const int b  = blockIdx.x;
    const int wt = (b & 1) * WTILE;   // 0 or 128
    const int nh = b >> 1;
    const int n  = nh / H_;
    const int h  = nh % H_;

    const size_t in_base = ((size_t)n * C_ * H_ + h) * W_;

    const int i0 = ig * DT;           // first disparity this thread owns
    const int w0 = wt + tw * VT;      // first w column this thread owns

    float acc[DT][VT];
    #pragma unroll
    for (int k = 0; k < DT; ++k)
        #pragma unroll
        for (int v = 0; v < VT; ++v) acc[k][v] = 0.f;

    // window f[m] = y_pad[w0 - i0 - 11 + m]; LDS col j = 48 + 4*tw + v - 12*ig - k
    // aligned start (mod 4 == 0): js = 4*tw - 12*ig + 36; use r_[m], m = 12+v-k in [1,15].
    const int js = 4 * tw - DT * ig + (HALO - DT + 1) - 1;   // in [0, 160]

    for (int ch = 0; ch < NCHUNK; ++ch) {
        const int c0 = ch * CCHUNK;

        // ---- stage y chunk: 16 rows x 44 float4 = 704 f4; 6 iters of 128 ----
        #pragma unroll
        for (int kk = 0; kk < 6; ++kk) {
            int idx = kk * NTHREADS + t;
            if (idx < CCHUNK * (YCOLS / 4)) {
                int r = idx / (YCOLS / 4);
                int q = idx % (YCOLS / 4);
                int w = wt - HALO + 4 * q;   // global w of this float4 (mod 4 == 0)
                float4 v;
                if (w >= 0)
                    v = *reinterpret_cast<const float4*>(
                        &y[in_base + (size_t)(c0 + r) * HW_ + w]);
                else
                    v = make_float4(0.f, 0.f, 0.f, 0.f);
                *reinterpret_cast<float4*>(&ysh[r][4 * q]) = v;
            }
        }
        // ---- stage x chunk: 16 rows x 32 float4 = 512 f4; 4 iters exact ----
        #pragma unroll
        for (int kk = 0; kk < 4; ++kk) {
            int idx = kk * NTHREADS + t;
            int r = idx / (WTILE / 4);
            int q = idx % (WTILE / 4);
            float4 v = *reinterpret_cast<const float4*>(
                &x[in_base + (size_t)(c0 + r) * HW_ + wt + 4 * q]);
            *reinterpret_cast<float4*>(&xsh[r][4 * q]) = v;
        }
        __syncthreads();

        #pragma unroll 4
        for (int cc = 0; cc < CCHUNK; ++cc) {
            // 15-float y window as 4 aligned b128 reads (r_[0] unused)
            const float4 q0 = *reinterpret_cast<const float4*>(&ysh[cc][js]);
            const float4 q1 = *reinterpret_cast<const float4*>(&ysh[cc][js + 4]);
            const float4 q2 = *reinterpret_cast<const float4*>(&ysh[cc][js + 8]);
            const float4 q3 = *reinterpret_cast<const float4*>(&ysh[cc][js + 12]);
            const float4 xq = *reinterpret_cast<const float4*>(&xsh[cc][tw * VT]);
            const float r_[16] = {q0.x, q0.y, q0.z, q0.w,
                                  q1.x, q1.y, q1.z, q1.w,
                                  q2.x, q2.y, q2.z, q2.w,
                                  q3.x, q3.y, q3.z, q3.w};
            const float xv[VT] = {xq.x, xq.y, xq.z, xq.w};
            // acc[k][v] += x[c, w0+v] * y[c, w0+v-(i0+k)] = xv[v]*r_[12+v-k]
            #pragma unroll
            for (int k = 0; k < DT; ++k)
                #pragma unroll
                for (int v = 0; v < VT; ++v)
                    acc[k][v] = fmaf(xv[v], r_[12 + v - k], acc[k][v]);
        }
        __syncthreads();
    }

    // ---- write out[n, i0+k, h, w0..w0+3]: 12 coalesced float4 stores ----
    const size_t ob = ((size_t)(n * D_ + i0) * H_ + h) * W_ + w0;
    #pragma unroll
    for (int k = 0; k < DT; ++k) {
        float4 o;
        o.x = acc[k][0]; o.y = acc[k][1]; o.z = acc[k][2]; o.w = acc[k][3];
        *reinterpret_cast<float4*>(&out[ob + (size_t)k * HW_]) = o;
    }
}

extern "C" void kernel_launch(void* const* d_in, const int* in_sizes, int n_in,
                              void* d_out, int out_size, void* d_ws, size_t ws_size,
                              hipStream_t stream) {
    (void)in_sizes; (void)n_in; (void)out_size; (void)d_ws; (void)ws_size;
    const float* x = (const float*)d_in[0];
    const float* y = (const float*)d_in[1];
    float* out = (float*)d_out;

    dim3 grid(N_ * H_ * (W_ / WTILE));   // 1024 blocks
    dim3 block(NTHREADS);                // 128 threads
    corr1d_v2<<<grid, block, 0, stream>>>(x, y, out);
}